// Round 15
// baseline (218.323 us; speedup 1.0000x reference)
//
#include <hip/hip_runtime.h>
#include <hip/hip_bf16.h>

#define NN 50000
#define NE 800000
#define DD 128
#define NCLS 40
#define NBK ((NN + 255) >> 8)      // 196 dst-buckets of 256 nodes
#define EPB 1024                   // edges per k_part block (4/thread)
#define PB ((NE + EPB - 1) / EPB)  // 782 partition blocks
#define CVB ((NN * DD / 4) / 256)  // 6250 cvt blocks
#define WB 384                     // weight-convert blocks (192 units x 2 halves)
#define SEMAX 5120                 // max edges per bucket (mean 4081, sd 64)
#define PR (NN + 1)                // plane rows (row NN = zeros for pad-gathers)
#define DCAP 48                    // staged-degree cap (Poisson(16): P(>48)~1e-10)
#define NCH64 ((NN + 63) / 64)     // 782 node-chunks of 64

typedef _Float16 f16x8 __attribute__((ext_vector_type(8)));  // 8 f16 (4 VGPRs)
typedef _Float16 f16x4 __attribute__((ext_vector_type(4)));
typedef float f32x4 __attribute__((ext_vector_type(4)));     // MFMA acc
typedef unsigned int u32x4 __attribute__((ext_vector_type(4)));  // NT-store-able

__device__ __forceinline__ unsigned int pack2h(_Float16 a, _Float16 b) {
    union { _Float16 h[2]; unsigned int u; } c;
    c.h[0] = a; c.h[1] = b;
    return c.u;
}
__device__ __forceinline__ void unpack2h(unsigned int p, float& a, float& b) {
    union { unsigned int u; _Float16 h[2]; } c;
    c.u = p;
    a = (float)c.h[0]; b = (float)c.h[1];
}

// Node feature tables (xh, aggh, h1h, h2h) are PLANE-MAJOR with PR rows:
//   plane p holds u16 cols [p*32, p*32+32): addr_u16 = (p*PR + node)*32 + c.
//   One plane = 3.2 MB -> fits a per-XCD L2 (4 MB); gathers pinned
//   plane->XCD-pair via blockIdx%8 (round-3-validated: FETCH 77.7->18.5 MB).
//   Row NN of every plane is ZERO: padded edge slots gather it harmlessly.
//   zh (layer-3 projected z) is now ALSO 2-plane-major (3.2 MB planes,
//   cols 0-31 / 32-63), pinned plane->XCD-half; row NN zero.

// ---------------------------------------------------------------------------
// Mega front kernel.
__global__ void k_front(const int* __restrict__ ei, int* __restrict__ cellcnt,
                        int* __restrict__ celloff, unsigned int* __restrict__ pairs,
                        const float* __restrict__ x, unsigned short* __restrict__ xh,
                        const float* __restrict__ w1l, const float* __restrict__ w1r,
                        const float* __restrict__ w2l, const float* __restrict__ w2r,
                        const float* __restrict__ w3l, const float* __restrict__ w3r,
                        unsigned short* __restrict__ bt1h,
                        unsigned short* __restrict__ bt2h,
                        unsigned short* __restrict__ bt3h,
                        unsigned short* __restrict__ h1h,
                        unsigned short* __restrict__ zh) {
    if (blockIdx.x >= PB + CVB) {
        int idx = blockIdx.x - (PB + CVB);
        if (idx == WB) {
            // ---- zero-row writer: row NN of xh/h1h planes and zh planes ----
            int t = threadIdx.x;
            if (t < 128) {
                int which = t >> 4;                 // 0..7
                unsigned int* buf = (unsigned int*)((which < 4) ? xh : h1h);
                int plane = which & 3;
                buf[((size_t)plane * PR + NN) * 16 + (t & 15)] = 0u;
            } else if (t < 160) {
                int plane = (t - 128) >> 4, c = (t - 128) & 15;
                ((unsigned int*)zh)[((size_t)plane * PR + NN) * 16 + c] = 0u;
            }
            return;
        }
        // ---- weight conversion (f16 hi only; error budget covers it) ----
        int w = idx >> 1, half = idx & 1;
        int ks = w & 7, tmp = w >> 3;
        int nt = tmp & 7, layer = tmp >> 3;
        const int NT = (layer == 2) ? 3 : 8;
        const int NC = (layer == 2) ? NCLS : DD;
        if (nt >= NT) return;
        const float* wl = (layer == 0) ? w1l : (layer == 1) ? w2l : w3l;
        const float* wr = (layer == 0) ? w1r : (layer == 1) ? w2r : w3r;
        unsigned short* bh = (layer == 0) ? bt1h : (layer == 1) ? bt2h : bt3h;
        int t = threadIdx.x;
        int j = t & 7, lane = (t >> 3) + half * 32;
        int row = nt * 16 + (lane & 15);          // output column n
        int k = ks * 32 + (lane >> 4) * 8 + j;    // K position in [Wl;Wr]
        float v = 0.f;
        if (row < NC)
            v = (k < 128) ? wl[(size_t)k * NC + row] : wr[(size_t)(k - 128) * NC + row];
        union { _Float16 f; unsigned short u; } ch;
        ch.f = (_Float16)v;
        bh[((size_t)(ks * NT + nt) * 64 + lane) * 8 + j] = ch.u;
        return;
    }
    if (blockIdx.x >= PB) {
        // ---- x conversion -> plane-major f16 ----
        int i = (blockIdx.x - PB) * 256 + threadIdx.x;  // float4 index
        float4 v = ((const float4*)x)[i];
        f16x4 h;
        h[0] = (_Float16)v.x; h[1] = (_Float16)v.y;
        h[2] = (_Float16)v.z; h[3] = (_Float16)v.w;
        int row = i >> 5;            // 32 float4 per 128-col row
        int f = i & 31;
        int plane = f >> 3;
        int pc = (f & 7) * 4;        // u16 col within plane
        *(f16x4*)(xh + ((size_t)plane * PR + row) * 32 + pc) = h;
        return;
    }
    // ---- edge partition: LDS bucket-sort, dense chunk out ----
    __shared__ int hist[NBK];
    __shared__ int s[256];
    __shared__ unsigned int sE[EPB];
    __shared__ int nz;
    const int t = threadIdx.x, blk = blockIdx.x;
    const int e0 = blk * EPB;
    if (t == 0) nz = 0;
    for (int i = t; i < NBK; i += 256) hist[i] = 0;
    __syncthreads();
    int any = 0;
    for (int i = t; i < EPB; i += 256)
        if (ei[2 * e0 + 2 * i + 1] != 0) any = 1;
    if (any) atomicOr(&nz, 1);
    __syncthreads();
    const int is64 = (nz == 0);
    unsigned int v[EPB / 256];
    int eb[EPB / 256], er[EPB / 256];
#pragma unroll
    for (int j = 0; j < EPB / 256; ++j) {
        int e = e0 + j * 256 + t;
        if (e < NE) {
            int sv, d;
            if (is64) { sv = ei[2 * e]; d = ei[2 * (NE + e)]; }
            else      { sv = ei[e];     d = ei[NE + e]; }
            v[j] = ((unsigned)sv << 16) | (unsigned)d;
            eb[j] = d >> 8;
            er[j] = atomicAdd(&hist[eb[j]], 1);
        } else {
            eb[j] = -1;
        }
    }
    __syncthreads();
    int hv = (t < NBK) ? hist[t] : 0;
    s[t] = hv;
    __syncthreads();
#pragma unroll
    for (int off = 1; off < 256; off <<= 1) {
        int u = (t >= off) ? s[t - off] : 0;
        __syncthreads();
        s[t] += u;
        __syncthreads();
    }
#pragma unroll
    for (int j = 0; j < EPB / 256; ++j)
        if (eb[j] >= 0) sE[s[eb[j]] - hist[eb[j]] + er[j]] = v[j];
    __syncthreads();
    ((uint4*)(pairs + (size_t)blk * EPB))[t] = ((const uint4*)sE)[t];
    for (int i = t; i < NBK; i += 256) {
        cellcnt[(size_t)i * PB + blk] = hist[i];
        celloff[(size_t)i * PB + blk] = s[i] - hist[i];
    }
}

// Bucket totals: 196 blocks, block b reduces its (coalesced) cellcnt row.
__global__ void k_scan_ba(const int* __restrict__ cellcnt, int* __restrict__ bsum) {
    __shared__ int red[256];
    int b = blockIdx.x, t = threadIdx.x;
    int acc = 0;
    for (int i = t; i < PB; i += 256) acc += cellcnt[(size_t)b * PB + i];
    red[t] = acc;
    __syncthreads();
#pragma unroll
    for (int off = 128; off > 0; off >>= 1) {
        if (t < off) red[t] += red[t + off];
        __syncthreads();
    }
    if (t == 0) bsum[b] = red[0];
}

// Phase 2 (+ folded bucket-base scan): one 512-thread block per bucket.
__global__ void k_fill2(const unsigned int* __restrict__ pairs,
                        const int* __restrict__ cellcnt,
                        const int* __restrict__ celloff,
                        const int* __restrict__ bsum,
                        int* __restrict__ row_ptr, unsigned short* __restrict__ srcs) {
    __shared__ unsigned int sE[SEMAX];
    __shared__ int hist[256];
    __shared__ int cur[256];
    __shared__ int sb[256];
    __shared__ int scnt;
    const int b = blockIdx.x, t = threadIdx.x;
    if (t < 256) {
        int v = (t < NBK) ? bsum[t] : 0;
        sb[t] = v;
    }
    if (t == 0) scnt = 0;
    if (t < 256) hist[t] = 0;
    __syncthreads();
#pragma unroll
    for (int off = 1; off < 256; off <<= 1) {
        int u = (t >= off && t < 256) ? sb[t - off] : 0;
        __syncthreads();
        if (t < 256) sb[t] += u;
        __syncthreads();
    }
    const int bbase = (b == 0) ? 0 : sb[b - 1];
    if (b == NBK - 1 && t == 0) row_ptr[NN] = sb[NBK - 1];
    for (int blk = t; blk < PB; blk += 512) {
        int cnt = cellcnt[(size_t)b * PB + blk];
        if (cnt) {
            int off = celloff[(size_t)b * PB + blk];
            int base = atomicAdd(&scnt, cnt);
            if (base + cnt <= SEMAX) {
                const unsigned int* pp = pairs + (size_t)blk * EPB + off;
                for (int j = 0; j < cnt; ++j) {
                    unsigned int v = pp[j];
                    sE[base + j] = v;
                    atomicAdd(&hist[v & 255u], 1);
                }
            }
        }
    }
    __syncthreads();
    int h = (t < 256) ? hist[t] : 0;
    if (t < 256) cur[t] = h;
    __syncthreads();
#pragma unroll
    for (int off = 1; off < 256; off <<= 1) {
        int u = (t >= off && t < 256) ? cur[t - off] : 0;
        __syncthreads();
        if (t < 256) cur[t] += u;
        __syncthreads();
    }
    if (t < 256) {
        int node = (b << 8) + t;
        int base = bbase + cur[t] - h;
        if (node < NN) row_ptr[node] = base;
        cur[t] = base;
    }
    __syncthreads();
    int total = min(scnt, SEMAX);
    for (int i = t; i < total; i += 512) {
        unsigned int v = sE[i];
        int pos = atomicAdd(&cur[v & 255u], 1);
        srcs[pos] = (unsigned short)(v >> 16);
    }
}

// ---------------------------------------------------------------------------
// Shared gather body: block = 64 nodes x 1 plane; wave = 16 nodes x 4 lanes,
// dwordx4 per lane -> one VMEM instruction = 16 edges x 64 B; 8 loads in
// flight. srcs staged in LDS padded with NN (zero row). Returns a[8] sums.
__device__ __forceinline__ void gather64(const uint4* __restrict__ tab,
                                         const unsigned short* __restrict__ srcs,
                                         const unsigned short* sSrc, const int* sRp,
                                         int ln, unsigned int pc, float* a,
                                         int& deg_out) {
    const int b = sRp[ln], e = sRp[ln + 1];
    const int deg = e - b;
    deg_out = deg;
    int dm = deg;
    dm = max(dm, __shfl_xor(dm, 4));
    dm = max(dm, __shfl_xor(dm, 8));
    dm = max(dm, __shfl_xor(dm, 16));
    dm = max(dm, __shfl_xor(dm, 32));
    const int nit = (min(dm, DCAP) + 7) >> 3;   // 8 edges / iteration, <= 6
    int sb = ln * DCAP;
    for (int it = 0; it < nit; ++it) {
        unsigned int s0 = sSrc[sb + 0];
        unsigned int s1 = sSrc[sb + 1];
        unsigned int s2 = sSrc[sb + 2];
        unsigned int s3 = sSrc[sb + 3];
        unsigned int s4 = sSrc[sb + 4];
        unsigned int s5 = sSrc[sb + 5];
        unsigned int s6 = sSrc[sb + 6];
        unsigned int s7 = sSrc[sb + 7];
        uint4 p0 = tab[s0 * 4u + pc];
        uint4 p1 = tab[s1 * 4u + pc];
        uint4 p2 = tab[s2 * 4u + pc];
        uint4 p3 = tab[s3 * 4u + pc];
        uint4 p4 = tab[s4 * 4u + pc];
        uint4 p5 = tab[s5 * 4u + pc];
        uint4 p6 = tab[s6 * 4u + pc];
        uint4 p7 = tab[s7 * 4u + pc];
        float u0, u1;
        unpack2h(p0.x, u0, u1); a[0] += u0; a[1] += u1;
        unpack2h(p0.y, u0, u1); a[2] += u0; a[3] += u1;
        unpack2h(p0.z, u0, u1); a[4] += u0; a[5] += u1;
        unpack2h(p0.w, u0, u1); a[6] += u0; a[7] += u1;
        unpack2h(p1.x, u0, u1); a[0] += u0; a[1] += u1;
        unpack2h(p1.y, u0, u1); a[2] += u0; a[3] += u1;
        unpack2h(p1.z, u0, u1); a[4] += u0; a[5] += u1;
        unpack2h(p1.w, u0, u1); a[6] += u0; a[7] += u1;
        unpack2h(p2.x, u0, u1); a[0] += u0; a[1] += u1;
        unpack2h(p2.y, u0, u1); a[2] += u0; a[3] += u1;
        unpack2h(p2.z, u0, u1); a[4] += u0; a[5] += u1;
        unpack2h(p2.w, u0, u1); a[6] += u0; a[7] += u1;
        unpack2h(p3.x, u0, u1); a[0] += u0; a[1] += u1;
        unpack2h(p3.y, u0, u1); a[2] += u0; a[3] += u1;
        unpack2h(p3.z, u0, u1); a[4] += u0; a[5] += u1;
        unpack2h(p3.w, u0, u1); a[6] += u0; a[7] += u1;
        unpack2h(p4.x, u0, u1); a[0] += u0; a[1] += u1;
        unpack2h(p4.y, u0, u1); a[2] += u0; a[3] += u1;
        unpack2h(p4.z, u0, u1); a[4] += u0; a[5] += u1;
        unpack2h(p4.w, u0, u1); a[6] += u0; a[7] += u1;
        unpack2h(p5.x, u0, u1); a[0] += u0; a[1] += u1;
        unpack2h(p5.y, u0, u1); a[2] += u0; a[3] += u1;
        unpack2h(p5.z, u0, u1); a[4] += u0; a[5] += u1;
        unpack2h(p5.w, u0, u1); a[6] += u0; a[7] += u1;
        unpack2h(p6.x, u0, u1); a[0] += u0; a[1] += u1;
        unpack2h(p6.y, u0, u1); a[2] += u0; a[3] += u1;
        unpack2h(p6.z, u0, u1); a[4] += u0; a[5] += u1;
        unpack2h(p6.w, u0, u1); a[6] += u0; a[7] += u1;
        unpack2h(p7.x, u0, u1); a[0] += u0; a[1] += u1;
        unpack2h(p7.y, u0, u1); a[2] += u0; a[3] += u1;
        unpack2h(p7.z, u0, u1); a[4] += u0; a[5] += u1;
        unpack2h(p7.w, u0, u1); a[6] += u0; a[7] += u1;
        sb += 8;
    }
    if (dm > DCAP) {                     // rare long-degree cleanup
        for (int k = DCAP; k < deg; ++k) {
            unsigned int s = (unsigned int)srcs[b + k];
            uint4 p = tab[s * 4u + pc];
            float u0, u1;
            unpack2h(p.x, u0, u1); a[0] += u0; a[1] += u1;
            unpack2h(p.y, u0, u1); a[2] += u0; a[3] += u1;
            unpack2h(p.z, u0, u1); a[4] += u0; a[5] += u1;
            unpack2h(p.w, u0, u1); a[6] += u0; a[7] += u1;
        }
    }
}

// Stage 64 nodes' srcs into LDS, padded with NN (zero row).
__device__ __forceinline__ void stage64(const unsigned short* __restrict__ srcs,
                                        unsigned short* sSrc, const int* sRp, int t) {
    int ln = t >> 2, k2 = t & 3;
    int b = sRp[ln], e = sRp[ln + 1];
#pragma unroll
    for (int m = 0; m < DCAP / 4; ++m) {
        int k = k2 + m * 4;
        sSrc[ln * DCAP + k] = (b + k < e) ? srcs[b + k] : (unsigned short)NN;
    }
}

// ---------------------------------------------------------------------------
// Plane-pinned mean aggregation v7 (layers 1-2). 4 planes -> XCD pairs.
__global__ __launch_bounds__(256, 8)
void k_aggp(const unsigned int* __restrict__ inq, const int* __restrict__ row_ptr,
            const unsigned short* __restrict__ srcs, unsigned int* __restrict__ oq) {
    __shared__ unsigned short sSrc[64 * DCAP];
    __shared__ int sRp[65];
    const int t = threadIdx.x;
    const int plane = (blockIdx.x & 7) >> 1;
    const int c = ((blockIdx.x >> 3) << 1) + (blockIdx.x & 1);  // 64-node chunk
    if (c >= NCH64) return;
    const int n0 = c * 64;
    if (t < 65) sRp[t] = row_ptr[min(n0 + t, NN)];
    __syncthreads();
    stage64(srcs, sSrc, sRp, t);
    __syncthreads();
    const int wave = t >> 6, lane = t & 63;
    const int ng = lane >> 2;            // node subgroup 0..15
    const unsigned int pc = lane & 3;    // uint4 col within 64 B plane row
    const int ln = (wave << 4) + ng;
    const uint4* __restrict__ tab = (const uint4*)inq + (size_t)plane * (PR * 4);
    float a[8] = {};
    int deg;
    gather64(tab, srcs, sSrc, sRp, ln, pc, a, deg);
    const int node = n0 + ln;
    if (node < NN) {
        float inv = 1.0f / (float)(deg > 0 ? deg : 1);
        u32x4 ov;
        ov.x = pack2h((_Float16)(a[0] * inv), (_Float16)(a[1] * inv));
        ov.y = pack2h((_Float16)(a[2] * inv), (_Float16)(a[3] * inv));
        ov.z = pack2h((_Float16)(a[4] * inv), (_Float16)(a[5] * inv));
        ov.w = pack2h((_Float16)(a[6] * inv), (_Float16)(a[7] * inv));
        u32x4* dst = (u32x4*)(oq + ((size_t)plane * PR + node) * 16) + pc;
        __builtin_nontemporal_store(ov, dst);
    }
}

// ---------------------------------------------------------------------------
// f16 MFMA GEMM, B (hi only) staged in LDS in fragment layout.
// A tables are plane-major (PR rows): plane = ks&3.
template <int NT, int KPS, bool PACKOUT>
__launch_bounds__(256, 4)
__global__ void k_mfma(const unsigned short* __restrict__ A1h,
                       const unsigned short* __restrict__ A2h,
                       const unsigned short* __restrict__ Bthf,
                       const float* __restrict__ bias, float* __restrict__ outf,
                       unsigned short* __restrict__ outh, const int NC) {
    constexpr int STAGE_ELEMS = KPS * NT * 64 * 8;
    constexpr int STAGE_U4 = STAGE_ELEMS / 8;
    __shared__ unsigned short sBh[STAGE_ELEMS];

    const int tid = threadIdx.x;
    const int wave = tid >> 6, lane = tid & 63;
    const int quad = lane >> 4, mr = lane & 15;
    const int m0 = blockIdx.x * 64 + wave * 16;
    const int row = m0 + mr;
    const bool rok = row < NN;

    f32x4 acc[NT] = {};
    const f16x8 zero = {};

    auto aload = [&](int ks) -> f16x8 {
        const unsigned short* base = (ks < 4) ? A1h : A2h;
        const int plane = ks & 3;
        return rok ? *(const f16x8*)(base + ((size_t)plane * PR + row) * 32 + quad * 8)
                   : zero;
    };

    f16x8 cah = aload(0), pah;

#pragma unroll
    for (int s = 0; s < 8 / KPS; ++s) {
        const uint4* gh = (const uint4*)(Bthf + (size_t)s * STAGE_ELEMS);
        uint4* lh = (uint4*)sBh;
        if (s) __syncthreads();
        for (int i = tid; i < STAGE_U4; i += 256) lh[i] = gh[i];
        __syncthreads();

#pragma unroll
        for (int kl = 0; kl < KPS; ++kl) {
            const int ks = s * KPS + kl;
            if (ks < 7) pah = aload(ks + 1);
#pragma unroll
            for (int n = 0; n < NT; ++n) {
                const int fo = ((kl * NT + n) * 64 + lane) * 8;
                f16x8 bh = *(const f16x8*)(sBh + fo);
                acc[n] = __builtin_amdgcn_mfma_f32_16x16x32_f16(cah, bh, acc[n], 0, 0, 0);
            }
            cah = pah;
        }
    }

    // Epilogue. C/D layout: col = lane&15, row = quad*4 + reg.
#pragma unroll
    for (int n = 0; n < NT; ++n) {
        int col = n * 16 + mr;
        float bv = (col < NC) ? bias[col] : 0.f;
#pragma unroll
        for (int r = 0; r < 4; ++r) {
            int orow = m0 + quad * 4 + r;
            if (orow < NN && col < NC) {
                float v = acc[n][r] + bv;
                v = v > 0.f ? v : 0.f;
                if (PACKOUT) {
                    union { _Float16 f; unsigned short u; } ch;
                    ch.f = (_Float16)v;
                    int pl = col >> 5, pcc = col & 31;
                    outh[((size_t)pl * PR + orow) * 32 + pcc] = ch.u;
                } else {
                    outf[(size_t)orow * NC + col] = v;
                }
            }
        }
    }
}

// ---------------------------------------------------------------------------
// Layer 3 pre-projection: z = h2 @ w3_l (f16, 2-plane-major, PR rows),
//                         y = h2 @ w3_r + b3 (f32, 40 cols). k=128 only.
// A is plane-major. Exploits mean-linearity: agg(h2)@w3_l == agg(h2@w3_l).
__global__ __launch_bounds__(256, 4)
void k_gemm3(const unsigned short* __restrict__ Ah,
             const unsigned short* __restrict__ Bthf,
             const float* __restrict__ bias,
             unsigned short* __restrict__ zh, float* __restrict__ yf) {
    __shared__ unsigned short sBh[8 * 3 * 64 * 8];  // 24 KB, all of B
    const int tid = threadIdx.x;
    const int wave = tid >> 6, lane = tid & 63;
    const int quad = lane >> 4, mr = lane & 15;
    const int m0 = blockIdx.x * 64 + wave * 16;
    const int row = m0 + mr;
    const bool rok = row < NN;

    const uint4* gh = (const uint4*)Bthf;
    uint4* lh = (uint4*)sBh;
    for (int i = tid; i < (8 * 3 * 64 * 8) / 8; i += 256) lh[i] = gh[i];

    const f16x8 zero = {};
    f16x8 a[4];
#pragma unroll
    for (int j = 0; j < 4; ++j)
        a[j] = rok ? *(const f16x8*)(Ah + ((size_t)j * PR + row) * 32 + quad * 8)
                   : zero;
    __syncthreads();

    f32x4 accl[3] = {}, accr[3] = {};
#pragma unroll
    for (int ks = 0; ks < 4; ++ks) {
#pragma unroll
        for (int n = 0; n < 3; ++n) {
            f16x8 bl = *(const f16x8*)(sBh + ((ks * 3 + n) * 64 + lane) * 8);
            accl[n] = __builtin_amdgcn_mfma_f32_16x16x32_f16(a[ks], bl, accl[n], 0, 0, 0);
            f16x8 br = *(const f16x8*)(sBh + (((ks + 4) * 3 + n) * 64 + lane) * 8);
            accr[n] = __builtin_amdgcn_mfma_f32_16x16x32_f16(a[ks], br, accr[n], 0, 0, 0);
        }
    }

#pragma unroll
    for (int n = 0; n < 3; ++n) {
        int col = n * 16 + mr;   // 0..47
        float bv = (col < NCLS) ? bias[col] : 0.f;
#pragma unroll
        for (int r = 0; r < 4; ++r) {
            int orow = m0 + quad * 4 + r;
            if (orow < NN) {
                union { _Float16 f; unsigned short u; } ch;
                ch.f = (_Float16)accl[n][r];
                int pl = col >> 5, pcc = col & 31;   // 2-plane zh
                zh[((size_t)pl * PR + orow) * 32 + pcc] = ch.u;
                if (col < NCLS) yf[(size_t)orow * 40 + col] = accr[n][r] + bv;
            }
        }
    }
}

// ---------------------------------------------------------------------------
// Layer 3 aggregation v4: zh split into 2 planes of 3.2 MB, plane pinned to
// an XCD half via blockIdx%8>>2 -> L2-resident gather (same proven v7
// structure as k_aggp). Plane 0 -> out cols 0..31; plane 1 lanes pc==0 ->
// cols 32..39 (cols 40..63 are zero-pad, discarded). out = relu(mean + y).
__global__ __launch_bounds__(256, 8)
void k_agg3(const unsigned int* __restrict__ zu,
            const int* __restrict__ row_ptr,
            const unsigned short* __restrict__ srcs,
            const float* __restrict__ yf, float* __restrict__ out) {
    __shared__ unsigned short sSrc[64 * DCAP];
    __shared__ int sRp[65];
    const int t = threadIdx.x;
    const int q = blockIdx.x & 7;
    const int plane = q >> 2;                       // XCDs 0-3 plane0, 4-7 plane1
    const int c = ((blockIdx.x >> 3) << 2) + (q & 3);  // 64-node chunk
    if (c >= NCH64) return;
    const int n0 = c * 64;
    if (t < 65) sRp[t] = row_ptr[min(n0 + t, NN)];
    __syncthreads();
    stage64(srcs, sSrc, sRp, t);
    __syncthreads();
    const int wave = t >> 6, lane = t & 63;
    const int ng = lane >> 2;            // node subgroup 0..15
    const unsigned int pc = lane & 3;    // uint4 col within 64 B plane row
    const int ln = (wave << 4) + ng;
    const uint4* __restrict__ tab = (const uint4*)zu + (size_t)plane * (PR * 4);
    float a[8] = {};
    int deg;
    gather64(tab, srcs, sSrc, sRp, ln, pc, a, deg);
    const int node = n0 + ln;
    const int gc8 = plane * 4 + (int)pc;            // 8-col group index (0..7)
    if (node < NN && gc8 < 5) {                     // real cols: gc8*8..gc8*8+7
        float inv = 1.0f / (float)(deg > 0 ? deg : 1);
        float4 y0 = ((const float4*)yf)[(size_t)node * 10 + gc8 * 2];
        float4 y1 = ((const float4*)yf)[(size_t)node * 10 + gc8 * 2 + 1];
        float4 o0, o1;
        o0.x = fmaxf(a[0] * inv + y0.x, 0.f);
        o0.y = fmaxf(a[1] * inv + y0.y, 0.f);
        o0.z = fmaxf(a[2] * inv + y0.z, 0.f);
        o0.w = fmaxf(a[3] * inv + y0.w, 0.f);
        o1.x = fmaxf(a[4] * inv + y1.x, 0.f);
        o1.y = fmaxf(a[5] * inv + y1.y, 0.f);
        o1.z = fmaxf(a[6] * inv + y1.z, 0.f);
        o1.w = fmaxf(a[7] * inv + y1.w, 0.f);
        ((float4*)out)[(size_t)node * 10 + gc8 * 2] = o0;
        ((float4*)out)[(size_t)node * 10 + gc8 * 2 + 1] = o1;
    }
}

// ---------------------------------------------------------------------------
extern "C" void kernel_launch(void* const* d_in, const int* in_sizes, int n_in,
                              void* d_out, int out_size, void* d_ws, size_t ws_size,
                              hipStream_t stream) {
    const float* x    = (const float*)d_in[0];
    const int*   ei   = (const int*)d_in[1];
    const float* w1_l = (const float*)d_in[2];
    const float* w1_r = (const float*)d_in[3];
    const float* b1   = (const float*)d_in[4];
    const float* w2_l = (const float*)d_in[5];
    const float* w2_r = (const float*)d_in[6];
    const float* b2   = (const float*)d_in[7];
    const float* w3_l = (const float*)d_in[8];
    const float* w3_r = (const float*)d_in[9];
    const float* b3   = (const float*)d_in[10];
    float* out = (float*)d_out;

    char* w = (char*)d_ws;
    size_t off = 0;
    auto alloc = [&](size_t bytes) -> void* {
        void* p = w + off;
        off += (bytes + 255) / 256 * 256;
        return p;
    };
    int* row_ptr = (int*)alloc((size_t)(NN + 1) * 4);
    unsigned short* srcs = (unsigned short*)alloc((size_t)NE * 2 + 64);
    int* cellcnt = (int*)alloc((size_t)NBK * PB * 4);
    int* celloff = (int*)alloc((size_t)NBK * PB * 4);
    int* bsum    = (int*)alloc((size_t)NBK * 4);
    unsigned int* pairs = (unsigned int*)alloc((size_t)PB * EPB * 4);
    unsigned short* xh   = (unsigned short*)alloc((size_t)4 * PR * 32 * 2);  // also h2h
    unsigned short* aggh = (unsigned short*)alloc((size_t)4 * PR * 32 * 2);
    unsigned short* h1h  = (unsigned short*)alloc((size_t)4 * PR * 32 * 2);
    unsigned short* zh   = (unsigned short*)alloc((size_t)2 * PR * 32 * 2);
    float*          yf   = (float*)alloc((size_t)NN * 40 * 4);
    unsigned short* bt1h = (unsigned short*)alloc((size_t)8 * 8 * 64 * 8 * 2);
    unsigned short* bt2h = (unsigned short*)alloc((size_t)8 * 8 * 64 * 8 * 2);
    unsigned short* bt3h = (unsigned short*)alloc((size_t)8 * 3 * 64 * 8 * 2);
    unsigned short* h2h = xh;  // x dead after layer-1 GEMM; zero-rows persist
    (void)ws_size;

    k_front<<<PB + CVB + WB + 1, 256, 0, stream>>>(ei, cellcnt, celloff, pairs, x, xh,
                                                   w1_l, w1_r, w2_l, w2_r, w3_l, w3_r,
                                                   bt1h, bt2h, bt3h, h1h, zh);
    k_scan_ba<<<NBK, 256, 0, stream>>>(cellcnt, bsum);
    k_fill2<<<NBK, 512, 0, stream>>>(pairs, cellcnt, celloff, bsum, row_ptr, srcs);

    const int gmb = (NN + 63) / 64;                    // 782 (GEMM m-blocks)
    const int gp  = 8 * ((NCH64 + 1) / 2);             // 3128 (4-plane blocks)
    const int gp3 = 8 * ((NCH64 + 3) / 4);             // 1568 (2-plane blocks)
    // Layer 1
    k_aggp<<<gp, 256, 0, stream>>>((const unsigned int*)xh, row_ptr, srcs,
                                   (unsigned int*)aggh);
    k_mfma<8, 4, true><<<gmb, 256, 0, stream>>>(aggh, xh, bt1h, b1,
                                                nullptr, h1h, DD);
    // Layer 2 (h2h aliases xh; x is dead)
    k_aggp<<<gp, 256, 0, stream>>>((const unsigned int*)h1h, row_ptr, srcs,
                                   (unsigned int*)aggh);
    k_mfma<8, 4, true><<<gmb, 256, 0, stream>>>(aggh, h1h, bt2h, b2,
                                                nullptr, h2h, DD);
    // Layer 3: pre-project then plane-pinned light aggregate
    k_gemm3<<<gmb, 256, 0, stream>>>(h2h, bt3h, b3, zh, yf);
    k_agg3<<<gp3, 256, 0, stream>>>((const unsigned int*)zh, row_ptr, srcs,
                                    yf, out);
}

// Round 16
// 217.787 us; speedup vs baseline: 1.0025x; 1.0025x over previous
//
#include <hip/hip_runtime.h>
#include <hip/hip_bf16.h>

#define NN 50000
#define NE 800000
#define DD 128
#define NCLS 40
#define NBK ((NN + 255) >> 8)      // 196 dst-buckets of 256 nodes
#define EPB 1024                   // edges per k_part block (4/thread)
#define PB ((NE + EPB - 1) / EPB)  // 782 partition blocks
#define CVB ((NN * DD / 4) / 256)  // 6250 cvt blocks
#define WB 384                     // weight-convert blocks (192 units x 2 halves)
#define SEMAX 5120                 // max edges per bucket (mean 4081, sd 64)
#define PR (NN + 1)                // plane rows (row NN = zeros for pad-gathers)
#define DCAP 48                    // staged-degree cap (Poisson(16): P(>48)~1e-10)
#define NCH ((NN + 31) / 32)       // 1563 node-chunks of 32 (k_agg3)
#define NCH64 ((NN + 63) / 64)     // 782 node-chunks of 64 (k_aggp)

typedef _Float16 f16x8 __attribute__((ext_vector_type(8)));  // 8 f16 (4 VGPRs)
typedef _Float16 f16x4 __attribute__((ext_vector_type(4)));
typedef float f32x4 __attribute__((ext_vector_type(4)));     // MFMA acc
typedef unsigned int u32x4 __attribute__((ext_vector_type(4)));  // NT-store-able

__device__ __forceinline__ unsigned int pack2h(_Float16 a, _Float16 b) {
    union { _Float16 h[2]; unsigned int u; } c;
    c.h[0] = a; c.h[1] = b;
    return c.u;
}
__device__ __forceinline__ void unpack2h(unsigned int p, float& a, float& b) {
    union { unsigned int u; _Float16 h[2]; } c;
    c.u = p;
    a = (float)c.h[0]; b = (float)c.h[1];
}

// Node feature tables (xh, aggh, h1h, h2h) are PLANE-MAJOR with PR rows:
//   plane p holds u16 cols [p*32, p*32+32): addr_u16 = (p*PR + node)*32 + c.
//   One plane = 3.2 MB -> fits a per-XCD L2 (4 MB); gathers pinned
//   plane->XCD-pair via blockIdx%8 (round-3-validated: FETCH 77.7->18.5 MB).
//   Row NN of every plane is ZERO: padded edge slots gather it harmlessly.
//   zh (layer-3 projected z) is row-major with PR rows; row NN zero.
//   (Round-14 lesson: 2-plane-pinning zh was neutral-negative — 6.4 MB
//   already caches well across aggregate L2; row-major zh is best.)

// ---------------------------------------------------------------------------
// Mega front kernel.
__global__ void k_front(const int* __restrict__ ei, int* __restrict__ cellcnt,
                        int* __restrict__ celloff, unsigned int* __restrict__ pairs,
                        const float* __restrict__ x, unsigned short* __restrict__ xh,
                        const float* __restrict__ w1l, const float* __restrict__ w1r,
                        const float* __restrict__ w2l, const float* __restrict__ w2r,
                        const float* __restrict__ w3l, const float* __restrict__ w3r,
                        unsigned short* __restrict__ bt1h,
                        unsigned short* __restrict__ bt2h,
                        unsigned short* __restrict__ bt3h,
                        unsigned short* __restrict__ h1h,
                        unsigned short* __restrict__ zh) {
    if (blockIdx.x >= PB + CVB) {
        int idx = blockIdx.x - (PB + CVB);
        if (idx == WB) {
            // ---- zero-row writer: row NN of xh/h1h planes and of zh ----
            int t = threadIdx.x;
            if (t < 128) {
                int which = t >> 4;                 // 0..7
                unsigned int* buf = (unsigned int*)((which < 4) ? xh : h1h);
                int plane = which & 3;
                buf[((size_t)plane * PR + NN) * 16 + (t & 15)] = 0u;
            } else if (t < 160) {
                ((unsigned int*)zh)[(size_t)NN * 32 + (t - 128)] = 0u;
            }
            return;
        }
        // ---- weight conversion (f16 hi only; error budget covers it) ----
        int w = idx >> 1, half = idx & 1;
        int ks = w & 7, tmp = w >> 3;
        int nt = tmp & 7, layer = tmp >> 3;
        const int NT = (layer == 2) ? 3 : 8;
        const int NC = (layer == 2) ? NCLS : DD;
        if (nt >= NT) return;
        const float* wl = (layer == 0) ? w1l : (layer == 1) ? w2l : w3l;
        const float* wr = (layer == 0) ? w1r : (layer == 1) ? w2r : w3r;
        unsigned short* bh = (layer == 0) ? bt1h : (layer == 1) ? bt2h : bt3h;
        int t = threadIdx.x;
        int j = t & 7, lane = (t >> 3) + half * 32;
        int row = nt * 16 + (lane & 15);          // output column n
        int k = ks * 32 + (lane >> 4) * 8 + j;    // K position in [Wl;Wr]
        float v = 0.f;
        if (row < NC)
            v = (k < 128) ? wl[(size_t)k * NC + row] : wr[(size_t)(k - 128) * NC + row];
        union { _Float16 f; unsigned short u; } ch;
        ch.f = (_Float16)v;
        bh[((size_t)(ks * NT + nt) * 64 + lane) * 8 + j] = ch.u;
        return;
    }
    if (blockIdx.x >= PB) {
        // ---- x conversion -> plane-major f16 ----
        int i = (blockIdx.x - PB) * 256 + threadIdx.x;  // float4 index
        float4 v = ((const float4*)x)[i];
        f16x4 h;
        h[0] = (_Float16)v.x; h[1] = (_Float16)v.y;
        h[2] = (_Float16)v.z; h[3] = (_Float16)v.w;
        int row = i >> 5;            // 32 float4 per 128-col row
        int f = i & 31;
        int plane = f >> 3;
        int pc = (f & 7) * 4;        // u16 col within plane
        *(f16x4*)(xh + ((size_t)plane * PR + row) * 32 + pc) = h;
        return;
    }
    // ---- edge partition: LDS bucket-sort, dense chunk out ----
    __shared__ int hist[NBK];
    __shared__ int s[256];
    __shared__ unsigned int sE[EPB];
    __shared__ int nz;
    const int t = threadIdx.x, blk = blockIdx.x;
    const int e0 = blk * EPB;
    if (t == 0) nz = 0;
    for (int i = t; i < NBK; i += 256) hist[i] = 0;
    __syncthreads();
    int any = 0;
    for (int i = t; i < EPB; i += 256)
        if (ei[2 * e0 + 2 * i + 1] != 0) any = 1;
    if (any) atomicOr(&nz, 1);
    __syncthreads();
    const int is64 = (nz == 0);
    unsigned int v[EPB / 256];
    int eb[EPB / 256], er[EPB / 256];
#pragma unroll
    for (int j = 0; j < EPB / 256; ++j) {
        int e = e0 + j * 256 + t;
        if (e < NE) {
            int sv, d;
            if (is64) { sv = ei[2 * e]; d = ei[2 * (NE + e)]; }
            else      { sv = ei[e];     d = ei[NE + e]; }
            v[j] = ((unsigned)sv << 16) | (unsigned)d;
            eb[j] = d >> 8;
            er[j] = atomicAdd(&hist[eb[j]], 1);
        } else {
            eb[j] = -1;
        }
    }
    __syncthreads();
    int hv = (t < NBK) ? hist[t] : 0;
    s[t] = hv;
    __syncthreads();
#pragma unroll
    for (int off = 1; off < 256; off <<= 1) {
        int u = (t >= off) ? s[t - off] : 0;
        __syncthreads();
        s[t] += u;
        __syncthreads();
    }
#pragma unroll
    for (int j = 0; j < EPB / 256; ++j)
        if (eb[j] >= 0) sE[s[eb[j]] - hist[eb[j]] + er[j]] = v[j];
    __syncthreads();
    ((uint4*)(pairs + (size_t)blk * EPB))[t] = ((const uint4*)sE)[t];
    for (int i = t; i < NBK; i += 256) {
        cellcnt[(size_t)i * PB + blk] = hist[i];
        celloff[(size_t)i * PB + blk] = s[i] - hist[i];
    }
}

// Bucket totals: 196 blocks, block b reduces its (coalesced) cellcnt row.
__global__ void k_scan_ba(const int* __restrict__ cellcnt, int* __restrict__ bsum) {
    __shared__ int red[256];
    int b = blockIdx.x, t = threadIdx.x;
    int acc = 0;
    for (int i = t; i < PB; i += 256) acc += cellcnt[(size_t)b * PB + i];
    red[t] = acc;
    __syncthreads();
#pragma unroll
    for (int off = 128; off > 0; off >>= 1) {
        if (t < off) red[t] += red[t + off];
        __syncthreads();
    }
    if (t == 0) bsum[b] = red[0];
}

// Phase 2 (+ folded bucket-base scan): one 512-thread block per bucket.
__global__ void k_fill2(const unsigned int* __restrict__ pairs,
                        const int* __restrict__ cellcnt,
                        const int* __restrict__ celloff,
                        const int* __restrict__ bsum,
                        int* __restrict__ row_ptr, unsigned short* __restrict__ srcs) {
    __shared__ unsigned int sE[SEMAX];
    __shared__ int hist[256];
    __shared__ int cur[256];
    __shared__ int sb[256];
    __shared__ int scnt;
    const int b = blockIdx.x, t = threadIdx.x;
    if (t < 256) {
        int v = (t < NBK) ? bsum[t] : 0;
        sb[t] = v;
    }
    if (t == 0) scnt = 0;
    if (t < 256) hist[t] = 0;
    __syncthreads();
#pragma unroll
    for (int off = 1; off < 256; off <<= 1) {
        int u = (t >= off && t < 256) ? sb[t - off] : 0;
        __syncthreads();
        if (t < 256) sb[t] += u;
        __syncthreads();
    }
    const int bbase = (b == 0) ? 0 : sb[b - 1];
    if (b == NBK - 1 && t == 0) row_ptr[NN] = sb[NBK - 1];
    for (int blk = t; blk < PB; blk += 512) {
        int cnt = cellcnt[(size_t)b * PB + blk];
        if (cnt) {
            int off = celloff[(size_t)b * PB + blk];
            int base = atomicAdd(&scnt, cnt);
            if (base + cnt <= SEMAX) {
                const unsigned int* pp = pairs + (size_t)blk * EPB + off;
                for (int j = 0; j < cnt; ++j) {
                    unsigned int v = pp[j];
                    sE[base + j] = v;
                    atomicAdd(&hist[v & 255u], 1);
                }
            }
        }
    }
    __syncthreads();
    int h = (t < 256) ? hist[t] : 0;
    if (t < 256) cur[t] = h;
    __syncthreads();
#pragma unroll
    for (int off = 1; off < 256; off <<= 1) {
        int u = (t >= off && t < 256) ? cur[t - off] : 0;
        __syncthreads();
        if (t < 256) cur[t] += u;
        __syncthreads();
    }
    if (t < 256) {
        int node = (b << 8) + t;
        int base = bbase + cur[t] - h;
        if (node < NN) row_ptr[node] = base;
        cur[t] = base;
    }
    __syncthreads();
    int total = min(scnt, SEMAX);
    for (int i = t; i < total; i += 512) {
        unsigned int v = sE[i];
        int pos = atomicAdd(&cur[v & 255u], 1);
        srcs[pos] = (unsigned short)(v >> 16);
    }
}

// ---------------------------------------------------------------------------
// Plane-pinned mean aggregation v7. Block = 64 nodes x 1 plane (plane from
// blockIdx%8 -> XCD pair). Wave = 16 nodes x 4 lanes, dwordx4 per lane ->
// one VMEM instruction covers 16 edges x 64 B = 1 KB; inner loop issues 8
// loads back-to-back (128 B/lane in flight). srcs staged in LDS padded with
// NN (zero row) -> no clamp/mask VALU. NT stores via u32x4 ext-vector.
__global__ __launch_bounds__(256, 8)
void k_aggp(const unsigned int* __restrict__ inq, const int* __restrict__ row_ptr,
            const unsigned short* __restrict__ srcs, unsigned int* __restrict__ oq) {
    __shared__ unsigned short sSrc[64 * DCAP];
    __shared__ int sRp[65];
    const int t = threadIdx.x;
    const int plane = (blockIdx.x & 7) >> 1;
    const int c = ((blockIdx.x >> 3) << 1) + (blockIdx.x & 1);  // 64-node chunk
    if (c >= NCH64) return;
    const int n0 = c * 64;
    if (t < 65) sRp[t] = row_ptr[min(n0 + t, NN)];
    __syncthreads();
    {   // stage + pad this block's srcs into LDS (64 nodes x 48 slots)
        int ln = t >> 2, k2 = t & 3;
        int b = sRp[ln], e = sRp[ln + 1];
#pragma unroll
        for (int m = 0; m < DCAP / 4; ++m) {
            int k = k2 + m * 4;
            sSrc[ln * DCAP + k] = (b + k < e) ? srcs[b + k] : (unsigned short)NN;
        }
    }
    __syncthreads();
    const int wave = t >> 6, lane = t & 63;
    const int ng = lane >> 2;            // node subgroup 0..15
    const unsigned int pc = lane & 3;    // uint4 col within 64 B plane row
    const int ln = (wave << 4) + ng;
    const uint4* __restrict__ tab = (const uint4*)inq + (size_t)plane * (PR * 4);
    const int b = sRp[ln], e = sRp[ln + 1];
    const int deg = e - b;
    int dm = deg;
    dm = max(dm, __shfl_xor(dm, 4));
    dm = max(dm, __shfl_xor(dm, 8));
    dm = max(dm, __shfl_xor(dm, 16));
    dm = max(dm, __shfl_xor(dm, 32));
    const int nit = (min(dm, DCAP) + 7) >> 3;   // 8 edges / iteration, <= 6
    float a[8] = {};
    int sb = ln * DCAP;
    for (int it = 0; it < nit; ++it) {
        unsigned int s0 = sSrc[sb + 0];
        unsigned int s1 = sSrc[sb + 1];
        unsigned int s2 = sSrc[sb + 2];
        unsigned int s3 = sSrc[sb + 3];
        unsigned int s4 = sSrc[sb + 4];
        unsigned int s5 = sSrc[sb + 5];
        unsigned int s6 = sSrc[sb + 6];
        unsigned int s7 = sSrc[sb + 7];
        uint4 p0 = tab[s0 * 4u + pc];
        uint4 p1 = tab[s1 * 4u + pc];
        uint4 p2 = tab[s2 * 4u + pc];
        uint4 p3 = tab[s3 * 4u + pc];
        uint4 p4 = tab[s4 * 4u + pc];
        uint4 p5 = tab[s5 * 4u + pc];
        uint4 p6 = tab[s6 * 4u + pc];
        uint4 p7 = tab[s7 * 4u + pc];
        float u0, u1;
        unpack2h(p0.x, u0, u1); a[0] += u0; a[1] += u1;
        unpack2h(p0.y, u0, u1); a[2] += u0; a[3] += u1;
        unpack2h(p0.z, u0, u1); a[4] += u0; a[5] += u1;
        unpack2h(p0.w, u0, u1); a[6] += u0; a[7] += u1;
        unpack2h(p1.x, u0, u1); a[0] += u0; a[1] += u1;
        unpack2h(p1.y, u0, u1); a[2] += u0; a[3] += u1;
        unpack2h(p1.z, u0, u1); a[4] += u0; a[5] += u1;
        unpack2h(p1.w, u0, u1); a[6] += u0; a[7] += u1;
        unpack2h(p2.x, u0, u1); a[0] += u0; a[1] += u1;
        unpack2h(p2.y, u0, u1); a[2] += u0; a[3] += u1;
        unpack2h(p2.z, u0, u1); a[4] += u0; a[5] += u1;
        unpack2h(p2.w, u0, u1); a[6] += u0; a[7] += u1;
        unpack2h(p3.x, u0, u1); a[0] += u0; a[1] += u1;
        unpack2h(p3.y, u0, u1); a[2] += u0; a[3] += u1;
        unpack2h(p3.z, u0, u1); a[4] += u0; a[5] += u1;
        unpack2h(p3.w, u0, u1); a[6] += u0; a[7] += u1;
        unpack2h(p4.x, u0, u1); a[0] += u0; a[1] += u1;
        unpack2h(p4.y, u0, u1); a[2] += u0; a[3] += u1;
        unpack2h(p4.z, u0, u1); a[4] += u0; a[5] += u1;
        unpack2h(p4.w, u0, u1); a[6] += u0; a[7] += u1;
        unpack2h(p5.x, u0, u1); a[0] += u0; a[1] += u1;
        unpack2h(p5.y, u0, u1); a[2] += u0; a[3] += u1;
        unpack2h(p5.z, u0, u1); a[4] += u0; a[5] += u1;
        unpack2h(p5.w, u0, u1); a[6] += u0; a[7] += u1;
        unpack2h(p6.x, u0, u1); a[0] += u0; a[1] += u1;
        unpack2h(p6.y, u0, u1); a[2] += u0; a[3] += u1;
        unpack2h(p6.z, u0, u1); a[4] += u0; a[5] += u1;
        unpack2h(p6.w, u0, u1); a[6] += u0; a[7] += u1;
        unpack2h(p7.x, u0, u1); a[0] += u0; a[1] += u1;
        unpack2h(p7.y, u0, u1); a[2] += u0; a[3] += u1;
        unpack2h(p7.z, u0, u1); a[4] += u0; a[5] += u1;
        unpack2h(p7.w, u0, u1); a[6] += u0; a[7] += u1;
        sb += 8;
    }
    if (dm > DCAP) {                     // rare long-degree cleanup
        for (int k = DCAP; k < deg; ++k) {
            unsigned int s = (unsigned int)srcs[b + k];
            uint4 p = tab[s * 4u + pc];
            float u0, u1;
            unpack2h(p.x, u0, u1); a[0] += u0; a[1] += u1;
            unpack2h(p.y, u0, u1); a[2] += u0; a[3] += u1;
            unpack2h(p.z, u0, u1); a[4] += u0; a[5] += u1;
            unpack2h(p.w, u0, u1); a[6] += u0; a[7] += u1;
        }
    }
    const int node = n0 + ln;
    if (node < NN) {
        float inv = 1.0f / (float)(deg > 0 ? deg : 1);
        u32x4 ov;
        ov.x = pack2h((_Float16)(a[0] * inv), (_Float16)(a[1] * inv));
        ov.y = pack2h((_Float16)(a[2] * inv), (_Float16)(a[3] * inv));
        ov.z = pack2h((_Float16)(a[4] * inv), (_Float16)(a[5] * inv));
        ov.w = pack2h((_Float16)(a[6] * inv), (_Float16)(a[7] * inv));
        u32x4* dst = (u32x4*)(oq + ((size_t)plane * PR + node) * 16) + pc;
        __builtin_nontemporal_store(ov, dst);
    }
}

// ---------------------------------------------------------------------------
// f16 MFMA GEMM, B (hi only) staged in LDS in fragment layout.
// A tables are plane-major (PR rows): plane = ks&3.
template <int NT, int KPS, bool PACKOUT>
__launch_bounds__(256, 4)
__global__ void k_mfma(const unsigned short* __restrict__ A1h,
                       const unsigned short* __restrict__ A2h,
                       const unsigned short* __restrict__ Bthf,
                       const float* __restrict__ bias, float* __restrict__ outf,
                       unsigned short* __restrict__ outh, const int NC) {
    constexpr int STAGE_ELEMS = KPS * NT * 64 * 8;
    constexpr int STAGE_U4 = STAGE_ELEMS / 8;
    __shared__ unsigned short sBh[STAGE_ELEMS];

    const int tid = threadIdx.x;
    const int wave = tid >> 6, lane = tid & 63;
    const int quad = lane >> 4, mr = lane & 15;
    const int m0 = blockIdx.x * 64 + wave * 16;
    const int row = m0 + mr;
    const bool rok = row < NN;

    f32x4 acc[NT] = {};
    const f16x8 zero = {};

    auto aload = [&](int ks) -> f16x8 {
        const unsigned short* base = (ks < 4) ? A1h : A2h;
        const int plane = ks & 3;
        return rok ? *(const f16x8*)(base + ((size_t)plane * PR + row) * 32 + quad * 8)
                   : zero;
    };

    f16x8 cah = aload(0), pah;

#pragma unroll
    for (int s = 0; s < 8 / KPS; ++s) {
        const uint4* gh = (const uint4*)(Bthf + (size_t)s * STAGE_ELEMS);
        uint4* lh = (uint4*)sBh;
        if (s) __syncthreads();
        for (int i = tid; i < STAGE_U4; i += 256) lh[i] = gh[i];
        __syncthreads();

#pragma unroll
        for (int kl = 0; kl < KPS; ++kl) {
            const int ks = s * KPS + kl;
            if (ks < 7) pah = aload(ks + 1);
#pragma unroll
            for (int n = 0; n < NT; ++n) {
                const int fo = ((kl * NT + n) * 64 + lane) * 8;
                f16x8 bh = *(const f16x8*)(sBh + fo);
                acc[n] = __builtin_amdgcn_mfma_f32_16x16x32_f16(cah, bh, acc[n], 0, 0, 0);
            }
            cah = pah;
        }
    }

    // Epilogue. C/D layout: col = lane&15, row = quad*4 + reg.
#pragma unroll
    for (int n = 0; n < NT; ++n) {
        int col = n * 16 + mr;
        float bv = (col < NC) ? bias[col] : 0.f;
#pragma unroll
        for (int r = 0; r < 4; ++r) {
            int orow = m0 + quad * 4 + r;
            if (orow < NN && col < NC) {
                float v = acc[n][r] + bv;
                v = v > 0.f ? v : 0.f;
                if (PACKOUT) {
                    union { _Float16 f; unsigned short u; } ch;
                    ch.f = (_Float16)v;
                    int pl = col >> 5, pcc = col & 31;
                    outh[((size_t)pl * PR + orow) * 32 + pcc] = ch.u;
                } else {
                    outf[(size_t)orow * NC + col] = v;
                }
            }
        }
    }
}

// ---------------------------------------------------------------------------
// Layer 3 pre-projection: z = h2 @ w3_l (f16, row-major 64-col-padded rows),
//                         y = h2 @ w3_r + b3 (f32, 40 cols). k=128 only.
// A is plane-major. Exploits mean-linearity: agg(h2)@w3_l == agg(h2@w3_l).
__global__ __launch_bounds__(256, 4)
void k_gemm3(const unsigned short* __restrict__ Ah,
             const unsigned short* __restrict__ Bthf,
             const float* __restrict__ bias,
             unsigned short* __restrict__ zh, float* __restrict__ yf) {
    __shared__ unsigned short sBh[8 * 3 * 64 * 8];  // 24 KB, all of B
    const int tid = threadIdx.x;
    const int wave = tid >> 6, lane = tid & 63;
    const int quad = lane >> 4, mr = lane & 15;
    const int m0 = blockIdx.x * 64 + wave * 16;
    const int row = m0 + mr;
    const bool rok = row < NN;

    const uint4* gh = (const uint4*)Bthf;
    uint4* lh = (uint4*)sBh;
    for (int i = tid; i < (8 * 3 * 64 * 8) / 8; i += 256) lh[i] = gh[i];

    const f16x8 zero = {};
    f16x8 a[4];
#pragma unroll
    for (int j = 0; j < 4; ++j)
        a[j] = rok ? *(const f16x8*)(Ah + ((size_t)j * PR + row) * 32 + quad * 8)
                   : zero;
    __syncthreads();

    f32x4 accl[3] = {}, accr[3] = {};
#pragma unroll
    for (int ks = 0; ks < 4; ++ks) {
#pragma unroll
        for (int n = 0; n < 3; ++n) {
            f16x8 bl = *(const f16x8*)(sBh + ((ks * 3 + n) * 64 + lane) * 8);
            accl[n] = __builtin_amdgcn_mfma_f32_16x16x32_f16(a[ks], bl, accl[n], 0, 0, 0);
            f16x8 br = *(const f16x8*)(sBh + (((ks + 4) * 3 + n) * 64 + lane) * 8);
            accr[n] = __builtin_amdgcn_mfma_f32_16x16x32_f16(a[ks], br, accr[n], 0, 0, 0);
        }
    }

#pragma unroll
    for (int n = 0; n < 3; ++n) {
        int col = n * 16 + mr;
        float bv = (col < NCLS) ? bias[col] : 0.f;
#pragma unroll
        for (int r = 0; r < 4; ++r) {
            int orow = m0 + quad * 4 + r;
            if (orow < NN) {
                union { _Float16 f; unsigned short u; } ch;
                ch.f = (_Float16)accl[n][r];
                zh[(size_t)orow * 64 + col] = ch.u;          // cols >=40 are 0 (B zero-padded)
                if (col < NCLS) yf[(size_t)orow * 40 + col] = accr[n][r] + bv;
            }
        }
    }
}

// ---------------------------------------------------------------------------
// Layer 3 aggregation v3 over projected z (PR rows x 64 f16 = 128 B; row NN
// zero). Block = 32 nodes, wave = 8 nodes x 8 lanes x dwordx4 -> one VMEM
// instruction = 8 edges x 128 B; inner loop issues 8 loads back-to-back.
// LDS-staged padded srcs -> no clamps. out = relu(mean + y).
__global__ __launch_bounds__(256, 8)
void k_agg3(const unsigned int* __restrict__ zu,
            const int* __restrict__ row_ptr,
            const unsigned short* __restrict__ srcs,
            const float* __restrict__ yf, float* __restrict__ out) {
    __shared__ unsigned short sSrc[32 * DCAP];
    __shared__ int sRp[33];
    const int t = threadIdx.x;
    const int c = blockIdx.x;           // 1563 chunks of 32 nodes
    const int n0 = c * 32;
    if (t < 33) sRp[t] = row_ptr[min(n0 + t, NN)];
    __syncthreads();
    {
        int ln = t >> 3, k2 = t & 7;
        int b = sRp[ln], e = sRp[ln + 1];
#pragma unroll
        for (int m = 0; m < DCAP / 8; ++m) {
            int k = k2 + m * 8;
            sSrc[ln * DCAP + k] = (b + k < e) ? srcs[b + k] : (unsigned short)NN;
        }
    }
    __syncthreads();
    const int wave = t >> 6, lane = t & 63;
    const int ng = lane >> 3;            // node subgroup 0..7
    const unsigned int pc = lane & 7;    // uint4 col (16 B) within 128 B row
    const int ln = (wave << 3) + ng;
    const uint4* __restrict__ tab = (const uint4*)zu;
    const int b = sRp[ln], e = sRp[ln + 1];
    const int deg = e - b;
    int dm = deg;
    dm = max(dm, __shfl_xor(dm, 8));
    dm = max(dm, __shfl_xor(dm, 16));
    dm = max(dm, __shfl_xor(dm, 32));
    const int nit = (min(dm, DCAP) + 7) >> 3;   // 8 edges / iteration, <= 6
    float a[8] = {};
    int sb = ln * DCAP;
    for (int it = 0; it < nit; ++it) {
        unsigned int s0 = sSrc[sb + 0];
        unsigned int s1 = sSrc[sb + 1];
        unsigned int s2 = sSrc[sb + 2];
        unsigned int s3 = sSrc[sb + 3];
        unsigned int s4 = sSrc[sb + 4];
        unsigned int s5 = sSrc[sb + 5];
        unsigned int s6 = sSrc[sb + 6];
        unsigned int s7 = sSrc[sb + 7];
        uint4 p0 = tab[s0 * 8u + pc];
        uint4 p1 = tab[s1 * 8u + pc];
        uint4 p2 = tab[s2 * 8u + pc];
        uint4 p3 = tab[s3 * 8u + pc];
        uint4 p4 = tab[s4 * 8u + pc];
        uint4 p5 = tab[s5 * 8u + pc];
        uint4 p6 = tab[s6 * 8u + pc];
        uint4 p7 = tab[s7 * 8u + pc];
        float u0, u1;
        unpack2h(p0.x, u0, u1); a[0] += u0; a[1] += u1;
        unpack2h(p0.y, u0, u1); a[2] += u0; a[3] += u1;
        unpack2h(p0.z, u0, u1); a[4] += u0; a[5] += u1;
        unpack2h(p0.w, u0, u1); a[6] += u0; a[7] += u1;
        unpack2h(p1.x, u0, u1); a[0] += u0; a[1] += u1;
        unpack2h(p1.y, u0, u1); a[2] += u0; a[3] += u1;
        unpack2h(p1.z, u0, u1); a[4] += u0; a[5] += u1;
        unpack2h(p1.w, u0, u1); a[6] += u0; a[7] += u1;
        unpack2h(p2.x, u0, u1); a[0] += u0; a[1] += u1;
        unpack2h(p2.y, u0, u1); a[2] += u0; a[3] += u1;
        unpack2h(p2.z, u0, u1); a[4] += u0; a[5] += u1;
        unpack2h(p2.w, u0, u1); a[6] += u0; a[7] += u1;
        unpack2h(p3.x, u0, u1); a[0] += u0; a[1] += u1;
        unpack2h(p3.y, u0, u1); a[2] += u0; a[3] += u1;
        unpack2h(p3.z, u0, u1); a[4] += u0; a[5] += u1;
        unpack2h(p3.w, u0, u1); a[6] += u0; a[7] += u1;
        unpack2h(p4.x, u0, u1); a[0] += u0; a[1] += u1;
        unpack2h(p4.y, u0, u1); a[2] += u0; a[3] += u1;
        unpack2h(p4.z, u0, u1); a[4] += u0; a[5] += u1;
        unpack2h(p4.w, u0, u1); a[6] += u0; a[7] += u1;
        unpack2h(p5.x, u0, u1); a[0] += u0; a[1] += u1;
        unpack2h(p5.y, u0, u1); a[2] += u0; a[3] += u1;
        unpack2h(p5.z, u0, u1); a[4] += u0; a[5] += u1;
        unpack2h(p5.w, u0, u1); a[6] += u0; a[7] += u1;
        unpack2h(p6.x, u0, u1); a[0] += u0; a[1] += u1;
        unpack2h(p6.y, u0, u1); a[2] += u0; a[3] += u1;
        unpack2h(p6.z, u0, u1); a[4] += u0; a[5] += u1;
        unpack2h(p6.w, u0, u1); a[6] += u0; a[7] += u1;
        unpack2h(p7.x, u0, u1); a[0] += u0; a[1] += u1;
        unpack2h(p7.y, u0, u1); a[2] += u0; a[3] += u1;
        unpack2h(p7.z, u0, u1); a[4] += u0; a[5] += u1;
        unpack2h(p7.w, u0, u1); a[6] += u0; a[7] += u1;
        sb += 8;
    }
    if (dm > DCAP) {
        for (int k = DCAP; k < deg; ++k) {
            unsigned int s = (unsigned int)srcs[b + k];
            uint4 p = tab[s * 8u + pc];
            float u0, u1;
            unpack2h(p.x, u0, u1); a[0] += u0; a[1] += u1;
            unpack2h(p.y, u0, u1); a[2] += u0; a[3] += u1;
            unpack2h(p.z, u0, u1); a[4] += u0; a[5] += u1;
            unpack2h(p.w, u0, u1); a[6] += u0; a[7] += u1;
        }
    }
    const int node = n0 + ln;
    if (node < NN && pc < 5) {           // real cols: pc*8 .. pc*8+7 (40 total)
        float inv = 1.0f / (float)(deg > 0 ? deg : 1);
        float4 y0 = ((const float4*)yf)[(size_t)node * 10 + pc * 2];
        float4 y1 = ((const float4*)yf)[(size_t)node * 10 + pc * 2 + 1];
        float4 o0, o1;
        o0.x = fmaxf(a[0] * inv + y0.x, 0.f);
        o0.y = fmaxf(a[1] * inv + y0.y, 0.f);
        o0.z = fmaxf(a[2] * inv + y0.z, 0.f);
        o0.w = fmaxf(a[3] * inv + y0.w, 0.f);
        o1.x = fmaxf(a[4] * inv + y1.x, 0.f);
        o1.y = fmaxf(a[5] * inv + y1.y, 0.f);
        o1.z = fmaxf(a[6] * inv + y1.z, 0.f);
        o1.w = fmaxf(a[7] * inv + y1.w, 0.f);
        ((float4*)out)[(size_t)node * 10 + pc * 2] = o0;
        ((float4*)out)[(size_t)node * 10 + pc * 2 + 1] = o1;
    }
}

// ---------------------------------------------------------------------------
extern "C" void kernel_launch(void* const* d_in, const int* in_sizes, int n_in,
                              void* d_out, int out_size, void* d_ws, size_t ws_size,
                              hipStream_t stream) {
    const float* x    = (const float*)d_in[0];
    const int*   ei   = (const int*)d_in[1];
    const float* w1_l = (const float*)d_in[2];
    const float* w1_r = (const float*)d_in[3];
    const float* b1   = (const float*)d_in[4];
    const float* w2_l = (const float*)d_in[5];
    const float* w2_r = (const float*)d_in[6];
    const float* b2   = (const float*)d_in[7];
    const float* w3_l = (const float*)d_in[8];
    const float* w3_r = (const float*)d_in[9];
    const float* b3   = (const float*)d_in[10];
    float* out = (float*)d_out;

    char* w = (char*)d_ws;
    size_t off = 0;
    auto alloc = [&](size_t bytes) -> void* {
        void* p = w + off;
        off += (bytes + 255) / 256 * 256;
        return p;
    };
    int* row_ptr = (int*)alloc((size_t)(NN + 1) * 4);
    unsigned short* srcs = (unsigned short*)alloc((size_t)NE * 2 + 64);
    int* cellcnt = (int*)alloc((size_t)NBK * PB * 4);
    int* celloff = (int*)alloc((size_t)NBK * PB * 4);
    int* bsum    = (int*)alloc((size_t)NBK * 4);
    unsigned int* pairs = (unsigned int*)alloc((size_t)PB * EPB * 4);
    unsigned short* xh   = (unsigned short*)alloc((size_t)4 * PR * 32 * 2);  // also h2h
    unsigned short* aggh = (unsigned short*)alloc((size_t)4 * PR * 32 * 2);
    unsigned short* h1h  = (unsigned short*)alloc((size_t)4 * PR * 32 * 2);
    unsigned short* zh   = (unsigned short*)alloc((size_t)PR * 64 * 2);
    float*          yf   = (float*)alloc((size_t)NN * 40 * 4);
    unsigned short* bt1h = (unsigned short*)alloc((size_t)8 * 8 * 64 * 8 * 2);
    unsigned short* bt2h = (unsigned short*)alloc((size_t)8 * 8 * 64 * 8 * 2);
    unsigned short* bt3h = (unsigned short*)alloc((size_t)8 * 3 * 64 * 8 * 2);
    unsigned short* h2h = xh;  // x dead after layer-1 GEMM; zero-rows persist
    (void)ws_size;

    k_front<<<PB + CVB + WB + 1, 256, 0, stream>>>(ei, cellcnt, celloff, pairs, x, xh,
                                                   w1_l, w1_r, w2_l, w2_r, w3_l, w3_r,
                                                   bt1h, bt2h, bt3h, h1h, zh);
    k_scan_ba<<<NBK, 256, 0, stream>>>(cellcnt, bsum);
    k_fill2<<<NBK, 512, 0, stream>>>(pairs, cellcnt, celloff, bsum, row_ptr, srcs);

    const int gmb = (NN + 63) / 64;                    // 782 (GEMM m-blocks)
    const int gp  = 8 * ((NCH64 + 1) / 2);             // 3128 (plane blocks)
    // Layer 1
    k_aggp<<<gp, 256, 0, stream>>>((const unsigned int*)xh, row_ptr, srcs,
                                   (unsigned int*)aggh);
    k_mfma<8, 4, true><<<gmb, 256, 0, stream>>>(aggh, xh, bt1h, b1,
                                                nullptr, h1h, DD);
    // Layer 2 (h2h aliases xh; x is dead)
    k_aggp<<<gp, 256, 0, stream>>>((const unsigned int*)h1h, row_ptr, srcs,
                                   (unsigned int*)aggh);
    k_mfma<8, 4, true><<<gmb, 256, 0, stream>>>(aggh, h1h, bt2h, b2,
                                                nullptr, h2h, DD);
    // Layer 3: pre-project then light aggregate
    k_gemm3<<<gmb, 256, 0, stream>>>(h2h, bt3h, b3, zh, yf);
    k_agg3<<<NCH, 256, 0, stream>>>((const unsigned int*)zh, row_ptr, srcs,
                                    yf, out);
}